// Round 10
// baseline (154.814 us; speedup 1.0000x reference)
//
#include <hip/hip_runtime.h>

#define WID 224
#define HGT 224
#define HWp 50176          // 224*224
#define CHW 150528         // 3*HWp
#define NB  64
#define NSL 2048           // 64 images x 32 slices
#define SCH 1568           // HWp/32
#define NT  9408           // 64*147 tiles of 1024 px
#define TPI 147            // tiles per image
#define TPC 49             // tiles per channel

// workspace offsets (4B units)
#define OFF_MAXB   0       // ints[0]: global max (float bits, atomicMax; poison is negative -> no init)
#define OFF_HIST1  256     // ints: 64*768 -> ends 49408
#define OFF_PSUM0  49408   // floats: 2048
#define OFF_PMIN0  51456   // floats: 2048*3
#define OFF_PMAX0  57600   // floats: 2048*3
#define OFF_PHIST0 63744   // ints: 2048*1536 (dual hist per slice: [0..768)=x1, [768..1536)=x255)
#define OFF_PSUM1  3209472 // floats: 9408*4 (per-wave partials)
#define OFF_PMIN1  3247104 // floats: 9408*4
#define OFF_PMAX1  3284736 // floats: 9408*4
#define OFF_INTER  3322368 // floats: 9,633,792  (ends 12,956,160 = 51.9 MB < ws)

__device__ __forceinline__ float clip255(float v){ return fminf(fmaxf(v, 0.f), 255.f); }

// wave-level reduce (64 lanes); lane 0 of each wave holds the result
__device__ __forceinline__ float wred(float v, int op){
    #pragma unroll
    for (int o = 32; o > 0; o >>= 1){
        float u = __shfl_down(v, o);
        v = (op==0) ? v+u : (op==1 ? fminf(v,u) : fmaxf(v,u));
    }
    return v;
}

// block reduce for 256 threads: shuffle + 4-slot LDS combine (2 barriers)
__device__ __forceinline__ float blk_reduce(float v, float* red, int tid, int op){
    float w = wred(v, op);
    if ((tid & 63) == 0) red[tid >> 6] = w;
    __syncthreads();
    float a = red[0], b = red[1], c = red[2], d = red[3];
    float r = (op==0) ? (a+b)+(c+d) : (op==1 ? fminf(fminf(a,b),fminf(c,d)) : fmaxf(fmaxf(a,b),fmaxf(c,d)));
    __syncthreads();
    return r;
}

// Parallel LUT build from per-thread bin count hv (thread tid owns bin tid).
// Hillis-Steele inclusive scan in shh; result LUT in slut. Returns slut.
__device__ __forceinline__ const float* lut_scan(int hv, int* shh, float* slut, int tid, int* h255){
    if (tid == 255) *h255 = hv;
    shh[tid] = hv;
    __syncthreads();
    #pragma unroll
    for (int off = 1; off < 256; off <<= 1){
        int v = (tid >= off) ? shh[tid-off] : 0;
        __syncthreads();
        shh[tid] += v;
        __syncthreads();
    }
    int cum = shh[tid] - hv;                 // exclusive prefix
    int step = (HWp - *h255) / 255;
    int l = (step > 0) ? min(max((cum + (step >> 1)) / step, 0), 255) : tid;
    slut[tid] = (float)l;
    __syncthreads();
    return slut;
}

__device__ __forceinline__ float samp(const float* __restrict__ pl, float yi, float xi, float scl){
    if (xi < 0.f || xi > (float)(WID-1) || yi < 0.f || yi > (float)(HGT-1)) return 0.f;
    return pl[(int)yi * WID + (int)xi] * scl;
}

// Compute 4 output px for plane-offset p of channel c; stats pre-resolved.
__device__ __forceinline__ void apply_body(const float* __restrict__ img,
                                           int c, int p,
                                           int j, int ap, float m, float scl,
                                           float mu, float lo, float hi,
                                           const float* lut,
                                           float o[4])
{
    int y = p / WID;
    int x = p - y*WID;
    const float* pl = img + c*HWp;
    float4 v4 = *(const float4*)(pl + p);
    float iv[4] = {v4.x*scl, v4.y*scl, v4.z*scl, v4.w*scl};

    if (!ap) {
        #pragma unroll
        for (int k = 0; k < 4; k++) o[k] = iv[k];
        return;
    }
    switch (j){
    case 0: case 1: case 2: case 3: case 4: {   // affine family
        float a = 1.f, bb = 0.f, cc = 0.f, dd = 0.f, ee = 1.f, ff = 0.f;
        if (j == 0)      bb = -0.3f + 0.6f*m;
        else if (j == 1) dd = -0.3f + 0.6f*m;
        else if (j == 2) cc = (-0.45f + 0.9f*m) * (float)WID;
        else if (j == 3) ff = (-0.45f + 0.9f*m) * (float)HGT;
        else {
            float deg = -30.f + 60.f*m;
            float rad = deg * (float)(3.14159265358979323846/180.0);
            float cs = cosf(rad), sn = sinf(rad);
            float cx = (WID-1)*0.5f, cy = (HGT-1)*0.5f;
            a = cs; bb = sn; dd = -sn; ee = cs;
            cc = cx - cs*cx - sn*cy;
            ff = cy + sn*cx - cs*cy;
        }
        float yf = (float)y;
        #pragma unroll
        for (int k = 0; k < 4; k++){
            float xf = (float)(x + k);
            float sx = a*xf + bb*yf + cc;
            float sy = dd*xf + ee*yf + ff;
            float x0f = floorf(sx), y0f = floorf(sy);
            float wx = sx - x0f, wy = sy - y0f;
            float v00 = samp(pl, y0f,     x0f,     scl);
            float v01 = samp(pl, y0f,     x0f+1.f, scl);
            float v10 = samp(pl, y0f+1.f, x0f,     scl);
            float v11 = samp(pl, y0f+1.f, x0f+1.f, scl);
            float top = v00*(1.f-wx) + v01*wx;
            float bot = v10*(1.f-wx) + v11*wx;
            o[k] = top*(1.f-wy) + bot*wy;
        }
        break; }
    case 5: {
        float f = 0.1f + 1.8f*m;
        #pragma unroll
        for (int k = 0; k < 4; k++) o[k] = clip255(iv[k]*f);
        break; }
    case 6: {
        float4 r4 = *(const float4*)(img + p);
        float4 g4 = *(const float4*)(img + HWp + p);
        float4 b4 = *(const float4*)(img + 2*HWp + p);
        float rr[4] = {r4.x*scl, r4.y*scl, r4.z*scl, r4.w*scl};
        float gg[4] = {g4.x*scl, g4.y*scl, g4.z*scl, g4.w*scl};
        float bl[4] = {b4.x*scl, b4.y*scl, b4.z*scl, b4.w*scl};
        float f = 0.1f + 1.8f*m;
        #pragma unroll
        for (int k = 0; k < 4; k++){
            float g = 0.299f*rr[k] + 0.587f*gg[k] + 0.114f*bl[k];
            o[k] = clip255(g + f*(iv[k] - g));
        }
        break; }
    case 7: {
        float f = 0.1f + 1.8f*m;
        #pragma unroll
        for (int k = 0; k < 4; k++){
            int xx = x + k;
            if (y == 0 || y == HGT-1 || xx == 0 || xx == WID-1) o[k] = iv[k];
            else {
                int q = p + k;
                float s8 = pl[q-WID-1] + pl[q-WID] + pl[q-WID+1]
                         + pl[q-1]     + pl[q+1]
                         + pl[q+WID-1] + pl[q+WID] + pl[q+WID+1];
                float blur = (s8*scl + 5.f*iv[k]) * (1.f/13.f);
                o[k] = clip255(blur + f*(iv[k] - blur));
            }
        }
        break; }
    case 8: {
        float f = 0.1f + 1.8f*m;
        #pragma unroll
        for (int k = 0; k < 4; k++) o[k] = clip255(mu + f*(iv[k] - mu));
        break; }
    case 9: {
        float thr = 256.f*m;
        #pragma unroll
        for (int k = 0; k < 4; k++) o[k] = (iv[k] < thr) ? iv[k] : 255.f - iv[k];
        break; }
    case 10: {
        float q = exp2f(rintf(4.f*m));
        #pragma unroll
        for (int k = 0; k < 4; k++) o[k] = floorf(iv[k]/q)*q;
        break; }
    case 11: {
        #pragma unroll
        for (int k = 0; k < 4; k++){
            int ivi = min(max((int)rintf(iv[k]), 0), 255);
            o[k] = lut[ivi];
        }
        break; }
    case 12: {
        float sc = 255.f / fmaxf(hi - lo, 1e-6f);
        #pragma unroll
        for (int k = 0; k < 4; k++)
            o[k] = (hi > lo) ? clip255((iv[k] - lo) * sc) : iv[k];
        break; }
    default:
        #pragma unroll
        for (int k = 0; k < 4; k++) o[k] = iv[k];
        break;
    }
}

// ---------------- K1: slice partials over x (2048 blocks) ----------------
__global__ void k1_stats(const float* __restrict__ x, const int* __restrict__ op,
                         const int* __restrict__ mask, float* __restrict__ wsf)
{
    __shared__ float red[4];
    __shared__ int sh[1536];
    int* ints = (int*)wsf;
    float* psum0 = wsf + OFF_PSUM0;
    float* pmin0 = wsf + OFF_PMIN0;
    float* pmax0 = wsf + OFF_PMAX0;
    int* phist0 = (int*)wsf + OFF_PHIST0;
    int* hist1  = (int*)wsf + OFF_HIST1;

    int bid = blockIdx.x, tid = threadIdx.x;
    int blk = ((bid & 7) << 8) + (bid >> 3);    // XCD swizzle: XCD x -> images [x*8, x*8+8)
    if (tid < 24) hist1[blk*24 + tid] = 0;      // zero 64*768 ints across 2048 blocks

    int b = blk >> 5, s = blk & 31;
    int j = op[b], ap = mask[b];
    bool needSum  = ap && (j == 8);
    bool needMM   = ap && (j == 12);
    bool needHist = ap && (j == 11);
    const float* img = x + (size_t)b * CHW;
    int p0 = s * SCH;
    const float GW[3] = {0.299f, 0.587f, 0.114f};

    float mx = 0.f, gs = 0.f;
    for (int c = 0; c < 3; c++){
        const float* pl = img + c*HWp + p0;
        float lo = 3.4e38f, hi = 0.f, cs = 0.f;
        for (int p = tid*4; p < SCH; p += 1024){
            float4 v = *(const float4*)(pl + p);
            float m4 = fmaxf(fmaxf(v.x, v.y), fmaxf(v.z, v.w));
            mx = fmaxf(mx, m4);
            if (needMM){ hi = fmaxf(hi, m4); lo = fminf(lo, fminf(fminf(v.x,v.y), fminf(v.z,v.w))); }
            if (needSum) cs += (v.x + v.y) + (v.z + v.w);
        }
        if (needSum) gs += GW[c] * cs;
        if (needMM){
            float l = blk_reduce(lo, red, tid, 1);
            if (!tid) pmin0[blk*3 + c] = l;
            float h = blk_reduce(hi, red, tid, 2);
            if (!tid) pmax0[blk*3 + c] = h;
        }
    }
    float bm = blk_reduce(mx, red, tid, 2);
    if (!tid) atomicMax(&ints[OFF_MAXB], __float_as_int(bm));   // bm>=0 -> int order == float order
    if (needSum){
        float t = blk_reduce(gs, red, tid, 0);
        if (!tid) psum0[blk] = t;
    }
    if (needHist){
        for (int i = tid; i < 1536; i += 256) sh[i] = 0;
        __syncthreads();
        for (int c = 0; c < 3; c++){
            const float* pl = img + c*HWp + p0;
            for (int p = tid; p < SCH; p += 256){
                float v = pl[p];
                atomicAdd(&sh[c*256 + min(max((int)rintf(v), 0), 255)], 1);
                atomicAdd(&sh[768 + c*256 + min(max((int)rintf(v*255.f), 0), 255)], 1);
            }
        }
        __syncthreads();
        for (int i = tid; i < 1536; i += 256) phist0[blk*1536 + i] = sh[i];
    }
}

// ---------------- K2: per-block finalize0 + apply depth0 + per-wave stats1 partials ----------------
__global__ void k2_apply0(const float* __restrict__ x, const float* __restrict__ ra,
                          const int* __restrict__ op, const int* __restrict__ mask,
                          float* __restrict__ wsf)
{
    __shared__ float red[4];
    __shared__ int   shh[256];
    __shared__ float slut[256];
    __shared__ int   h255;
    const int* ints = (const int*)wsf;
    const float* psum0 = wsf + OFF_PSUM0;
    const float* pmin0 = wsf + OFF_PMIN0;
    const float* pmax0 = wsf + OFF_PMAX0;
    const int* phist0 = (const int*)wsf + OFF_PHIST0;
    int* hist1 = (int*)wsf + OFF_HIST1;
    float* psum1 = wsf + OFF_PSUM1;
    float* pmin1 = wsf + OFF_PMIN1;
    float* pmax1 = wsf + OFF_PMAX1;
    float* inter = wsf + OFF_INTER;

    int bid = blockIdx.x, tid = threadIdx.x;
    int t = ((bid & 7) * 1176) + (bid >> 3);    // XCD swizzle: XCD x -> images [x*8, x*8+8)
    int b = t / TPI;
    int r = t - b*TPI;
    int c = r / TPC;
    int p = (r - c*TPC)*1024 + tid*4;

    float scl = (__int_as_float(ints[OFF_MAXB]) <= 1.0f) ? 255.f : 1.f;
    int j = op[b], ap = mask[b];
    float m = ra[b];

    // per-block finalize of stats0 (cheap, redundant across the image's blocks)
    float mu = 0.f, lo = 0.f, hi = 0.f;
    const float* lut = nullptr;
    if (ap){
        if (j == 8){
            float v = (tid < 32) ? psum0[b*32 + tid] : 0.f;
            mu = blk_reduce(v, red, tid, 0) * scl * (1.f/(float)HWp);
        } else if (j == 12){
            float v  = (tid < 32) ? pmin0[(b*32 + tid)*3 + c] : 3.4e38f;
            lo = blk_reduce(v, red, tid, 1) * scl;
            float v2 = (tid < 32) ? pmax0[(b*32 + tid)*3 + c] : 0.f;
            hi = blk_reduce(v2, red, tid, 2) * scl;
        } else if (j == 11){
            int d = (scl == 255.f) ? 1 : 0;
            const int* ph = phist0 + d*768 + c*256 + tid;
            int sum = 0;
            #pragma unroll 8
            for (int s = 0; s < 32; s++) sum += ph[(b*32 + s)*1536];
            lut = lut_scan(sum, shh, slut, tid, &h255);
        }
    }

    float o[4];
    apply_body(x + (size_t)b*CHW, c, p, j, ap, m, scl, mu, lo, hi, lut, o);
    float4 w = {o[0], o[1], o[2], o[3]};
    *(float4*)(inter + (size_t)b*CHW + c*HWp + p) = w;

    // fused stats1 partials on outputs: per-wave slots, no extra barriers
    int j1 = op[NB + b], ap1 = mask[NB + b];
    if (ap1 && (j1 == 8 || j1 == 11 || j1 == 12)){
        const float GW[3] = {0.299f, 0.587f, 0.114f};
        int wv = tid >> 6;
        if (j1 == 8){
            float s4 = (o[0] + o[1]) + (o[2] + o[3]);
            float ws = wred(s4, 0);
            if ((tid & 63) == 0) psum1[t*4 + wv] = ws * GW[c];
        } else if (j1 == 12){
            float l4 = fminf(fminf(o[0],o[1]), fminf(o[2],o[3]));
            float h4 = fmaxf(fmaxf(o[0],o[1]), fmaxf(o[2],o[3]));
            float wl = wred(l4, 1);
            float wh = wred(h4, 2);
            if ((tid & 63) == 0){ pmin1[t*4 + wv] = wl; pmax1[t*4 + wv] = wh; }
        } else {
            __syncthreads();              // shh free after lut_scan / unused otherwise
            shh[tid] = 0;
            __syncthreads();
            #pragma unroll
            for (int k = 0; k < 4; k++)
                atomicAdd(&shh[min(max((int)rintf(o[k]), 0), 255)], 1);
            __syncthreads();
            int v = shh[tid];
            if (v) atomicAdd(&hist1[b*768 + c*256 + tid], v);
        }
    }
}

// ---------------- K3: per-block finalize1 + apply depth1 -> out ----------------
__global__ void k3_apply1(const float* __restrict__ ra, const int* __restrict__ op,
                          const int* __restrict__ mask, float* __restrict__ out,
                          float* __restrict__ wsf)
{
    __shared__ float red[4];
    __shared__ int   shh[256];
    __shared__ float slut[256];
    __shared__ int   h255;
    const int* hist1 = (const int*)wsf + OFF_HIST1;
    const float* psum1 = wsf + OFF_PSUM1;
    const float* pmin1 = wsf + OFF_PMIN1;
    const float* pmax1 = wsf + OFF_PMAX1;
    const float* inter = wsf + OFF_INTER;

    int bid = blockIdx.x, tid = threadIdx.x;
    int t = ((bid & 7) * 1176) + (bid >> 3);    // XCD swizzle (same image->XCD map as K2)
    int b = t / TPI;
    int r = t - b*TPI;
    int c = r / TPC;
    int p = (r - c*TPC)*1024 + tid*4;

    int j = op[NB + b], ap = mask[NB + b];
    float m = ra[NB + b];

    float mu = 0.f, lo = 0.f, hi = 0.f;
    const float* lut = nullptr;
    if (ap){
        if (j == 8){
            float v = 0.f;
            for (int i = tid; i < TPI*4; i += 256) v += psum1[b*TPI*4 + i];
            mu = blk_reduce(v, red, tid, 0) * (1.f/(float)HWp);
        } else if (j == 12){
            float v  = (tid < TPC*4) ? pmin1[(b*TPI + c*TPC)*4 + tid] : 3.4e38f;
            lo = blk_reduce(v, red, tid, 1);
            float v2 = (tid < TPC*4) ? pmax1[(b*TPI + c*TPC)*4 + tid] : 0.f;
            hi = blk_reduce(v2, red, tid, 2);
        } else if (j == 11){
            lut = lut_scan(hist1[b*768 + c*256 + tid], shh, slut, tid, &h255);
        }
    }

    float o[4];
    apply_body(inter + (size_t)b*CHW, c, p, j, ap, m, 1.f, mu, lo, hi, lut, o);
    float4 w;
    w.x = fminf(fmaxf(o[0]*(1.f/255.f), 0.f), 1.f);
    w.y = fminf(fmaxf(o[1]*(1.f/255.f), 0.f), 1.f);
    w.z = fminf(fmaxf(o[2]*(1.f/255.f), 0.f), 1.f);
    w.w = fminf(fmaxf(o[3]*(1.f/255.f), 0.f), 1.f);
    *(float4*)(out + (size_t)b*CHW + c*HWp + p) = w;
}

extern "C" void kernel_launch(void* const* d_in, const int* in_sizes, int n_in,
                              void* d_out, int out_size, void* d_ws, size_t ws_size,
                              hipStream_t stream) {
    const float* x    = (const float*)d_in[0];
    const float* ra   = (const float*)d_in[1];
    const int*   op   = (const int*)d_in[2];
    const int*   mask = (const int*)d_in[3];
    float* out = (float*)d_out;
    float* wsf = (float*)d_ws;

    k1_stats <<<NSL, 256, 0, stream>>>(x, op, mask, wsf);
    k2_apply0<<<NT,  256, 0, stream>>>(x, ra, op, mask, wsf);
    k3_apply1<<<NT,  256, 0, stream>>>(ra, op, mask, out, wsf);
}

// Round 11
// 145.122 us; speedup vs baseline: 1.0668x; 1.0668x over previous
//
#include <hip/hip_runtime.h>

#define WID 224
#define HGT 224
#define HWp 50176          // 224*224
#define CHW 150528         // 3*HWp
#define NB  64
#define NSL 2048           // 64 images x 32 slices
#define SCH 1568           // HWp/32
#define NT  9408           // 64*147 tiles of 1024 px
#define TPI 147            // tiles per image
#define TPC 49             // tiles per channel

// workspace offsets (4B units)
#define OFF_MAXB   0       // ints[0]: global max (float bits, atomicMax; poison is negative -> no init)
#define OFF_HIST1  256     // ints: 64*768 -> ends 49408
#define OFF_PSUM0  49408   // floats: 2048
#define OFF_PMIN0  51456   // floats: 2048*3
#define OFF_PMAX0  57600   // floats: 2048*3
#define OFF_PHIST0 63744   // ints: 2048*1536 (dual hist per slice: [0..768)=x1, [768..1536)=x255)
#define OFF_PSUM1  3209472 // floats: 9408*4 (per-wave partials)
#define OFF_PMIN1  3247104 // floats: 9408*4
#define OFF_PMAX1  3284736 // floats: 9408*4
#define OFF_INTER  3322368 // floats: 9,633,792

__device__ __forceinline__ float clip255(float v){ return fminf(fmaxf(v, 0.f), 255.f); }

// wave-level reduce (64 lanes); lane 0 holds result
__device__ __forceinline__ float wred(float v, int op){
    #pragma unroll
    for (int o = 32; o > 0; o >>= 1){
        float u = __shfl_down(v, o);
        v = (op==0) ? v+u : (op==1 ? fminf(v,u) : fmaxf(v,u));
    }
    return v;
}

// block reduce for 256 threads: shuffle + 4-slot LDS combine (2 barriers)
__device__ __forceinline__ float blk_reduce(float v, float* red, int tid, int op){
    float w = wred(v, op);
    if ((tid & 63) == 0) red[tid >> 6] = w;
    __syncthreads();
    float a = red[0], b = red[1], c = red[2], d = red[3];
    float r = (op==0) ? (a+b)+(c+d) : (op==1 ? fminf(fminf(a,b),fminf(c,d)) : fmaxf(fmaxf(a,b),fmaxf(c,d)));
    __syncthreads();
    return r;
}

// Parallel LUT build from per-thread bin count hv (thread tid owns bin tid).
__device__ __forceinline__ const float* lut_scan(int hv, int* shh, float* slut, int tid, int* h255){
    if (tid == 255) *h255 = hv;
    shh[tid] = hv;
    __syncthreads();
    #pragma unroll
    for (int off = 1; off < 256; off <<= 1){
        int v = (tid >= off) ? shh[tid-off] : 0;
        __syncthreads();
        shh[tid] += v;
        __syncthreads();
    }
    int cum = shh[tid] - hv;                 // exclusive prefix
    int step = (HWp - *h255) / 255;
    int l = (step > 0) ? min(max((cum + (step >> 1)) / step, 0), 255) : tid;
    slut[tid] = (float)l;
    __syncthreads();
    return slut;
}

__device__ __forceinline__ float samp(const float* __restrict__ pl, float yi, float xi, float scl){
    if (xi < 0.f || xi > (float)(WID-1) || yi < 0.f || yi > (float)(HGT-1)) return 0.f;
    return pl[(int)yi * WID + (int)xi] * scl;
}

// Compute 4 output px for plane-offset p of channel c; v4 = raw (unscaled) input float4.
__device__ __forceinline__ void apply_body(const float* __restrict__ img,
                                           int c, int p, float4 v4,
                                           int j, int ap, float m, float scl,
                                           float mu, float lo, float hi,
                                           const float* lut,
                                           float o[4])
{
    int y = p / WID;
    int x = p - y*WID;
    const float* pl = img + c*HWp;
    float vr[4] = {v4.x, v4.y, v4.z, v4.w};
    float iv[4] = {v4.x*scl, v4.y*scl, v4.z*scl, v4.w*scl};

    if (!ap) {
        #pragma unroll
        for (int k = 0; k < 4; k++) o[k] = iv[k];
        return;
    }
    switch (j){
    case 0: case 2: {   // shear_x / translate_x: sy=y exactly (wy=0); sx steps by exactly 1
        float off = (j==0) ? (-0.3f + 0.6f*m)*(float)y
                           : (-0.45f + 0.9f*m)*(float)WID;
        float sx0 = (float)x + off;
        float x0f = floorf(sx0);
        float wx  = sx0 - x0f;
        int   x0  = (int)x0f;
        const float* row = pl + y*WID;
        float v[5];
        #pragma unroll
        for (int k = 0; k < 5; k++){
            int col = x0 + k;
            v[k] = (col >= 0 && col < WID) ? row[col]*scl : 0.f;
        }
        #pragma unroll
        for (int k = 0; k < 4; k++) o[k] = v[k]*(1.f-wx) + v[k+1]*wx;
        break; }
    case 3: {           // translate_y: sx=x exactly (wx=0); wy constant per row
        float ff  = (-0.45f + 0.9f*m)*(float)HGT;
        float sy0 = (float)y + ff;
        float y0f = floorf(sy0);
        float wy  = sy0 - y0f;
        int   y0  = (int)y0f;
        float4 t4 = {0.f,0.f,0.f,0.f}, b4 = {0.f,0.f,0.f,0.f};
        if (y0   >= 0 && y0   < HGT) t4 = *(const float4*)(pl + y0*WID + x);
        if (y0+1 >= 0 && y0+1 < HGT) b4 = *(const float4*)(pl + (y0+1)*WID + x);
        float tt[4] = {t4.x,t4.y,t4.z,t4.w}, bb[4] = {b4.x,b4.y,b4.z,b4.w};
        #pragma unroll
        for (int k = 0; k < 4; k++) o[k] = (tt[k]*scl)*(1.f-wy) + (bb[k]*scl)*wy;
        break; }
    case 1: {           // shear_y: sx=x exactly (wx=0); 2 loads per px
        float dd = -0.3f + 0.6f*m;
        #pragma unroll
        for (int k = 0; k < 4; k++){
            float sy = dd*(float)(x+k) + (float)y;
            float y0f = floorf(sy);
            float wy  = sy - y0f;
            int   y0  = (int)y0f;
            int col = x + k;
            float tv = (y0   >= 0 && y0   < HGT) ? pl[y0*WID + col]*scl : 0.f;
            float bv = (y0+1 >= 0 && y0+1 < HGT) ? pl[(y0+1)*WID + col]*scl : 0.f;
            o[k] = tv*(1.f-wy) + bv*wy;
        }
        break; }
    case 4: {           // rotate: general bilinear
        float deg = -30.f + 60.f*m;
        float rad = deg * (float)(3.14159265358979323846/180.0);
        float cs = cosf(rad), sn = sinf(rad);
        float cx = (WID-1)*0.5f, cy = (HGT-1)*0.5f;
        float a = cs, bb = sn, dd = -sn, ee = cs;
        float cc = cx - cs*cx - sn*cy;
        float ff = cy + sn*cx - cs*cy;
        float yf = (float)y;
        #pragma unroll
        for (int k = 0; k < 4; k++){
            float xf = (float)(x + k);
            float sx = a*xf + bb*yf + cc;
            float sy = dd*xf + ee*yf + ff;
            float x0f = floorf(sx), y0f = floorf(sy);
            float wx = sx - x0f, wy = sy - y0f;
            float v00 = samp(pl, y0f,     x0f,     scl);
            float v01 = samp(pl, y0f,     x0f+1.f, scl);
            float v10 = samp(pl, y0f+1.f, x0f,     scl);
            float v11 = samp(pl, y0f+1.f, x0f+1.f, scl);
            float top = v00*(1.f-wx) + v01*wx;
            float bot = v10*(1.f-wx) + v11*wx;
            o[k] = top*(1.f-wy) + bot*wy;
        }
        break; }
    case 5: {
        float f = 0.1f + 1.8f*m;
        #pragma unroll
        for (int k = 0; k < 4; k++) o[k] = clip255(iv[k]*f);
        break; }
    case 6: {
        float4 r4 = *(const float4*)(img + p);
        float4 g4 = *(const float4*)(img + HWp + p);
        float4 b4 = *(const float4*)(img + 2*HWp + p);
        float rr[4] = {r4.x*scl, r4.y*scl, r4.z*scl, r4.w*scl};
        float gg[4] = {g4.x*scl, g4.y*scl, g4.z*scl, g4.w*scl};
        float bl[4] = {b4.x*scl, b4.y*scl, b4.z*scl, b4.w*scl};
        float f = 0.1f + 1.8f*m;
        #pragma unroll
        for (int k = 0; k < 4; k++){
            float g = 0.299f*rr[k] + 0.587f*gg[k] + 0.114f*bl[k];
            o[k] = clip255(g + f*(iv[k] - g));
        }
        break; }
    case 7: {           // sharpness: 2 float4 + 6 scalar edge loads
        float f = 0.1f + 1.8f*m;
        if (y == 0 || y == HGT-1){
            #pragma unroll
            for (int k = 0; k < 4; k++) o[k] = iv[k];
        } else {
            float4 up4 = *(const float4*)(pl + p - WID);
            float4 dn4 = *(const float4*)(pl + p + WID);
            bool hasL = (x > 0), hasR = (x < WID-4);
            float u0 = hasL ? pl[p-WID-1] : 0.f, u5 = hasR ? pl[p-WID+4] : 0.f;
            float c0 = hasL ? pl[p-1]     : 0.f, c5 = hasR ? pl[p+4]     : 0.f;
            float d0 = hasL ? pl[p+WID-1] : 0.f, d5 = hasR ? pl[p+WID+4] : 0.f;
            float uu[6] = {u0, up4.x, up4.y, up4.z, up4.w, u5};
            float cc[6] = {c0, vr[0], vr[1], vr[2], vr[3], c5};
            float dd[6] = {d0, dn4.x, dn4.y, dn4.z, dn4.w, d5};
            #pragma unroll
            for (int k = 0; k < 4; k++){
                int xx = x + k;
                if (xx == 0 || xx == WID-1) o[k] = iv[k];
                else {
                    float s8 = uu[k]+uu[k+1]+uu[k+2] + cc[k]+cc[k+2] + dd[k]+dd[k+1]+dd[k+2];
                    float blur = (s8*scl + 5.f*iv[k]) * (1.f/13.f);
                    o[k] = clip255(blur + f*(iv[k] - blur));
                }
            }
        }
        break; }
    case 8: {
        float f = 0.1f + 1.8f*m;
        #pragma unroll
        for (int k = 0; k < 4; k++) o[k] = clip255(mu + f*(iv[k] - mu));
        break; }
    case 9: {
        float thr = 256.f*m;
        #pragma unroll
        for (int k = 0; k < 4; k++) o[k] = (iv[k] < thr) ? iv[k] : 255.f - iv[k];
        break; }
    case 10: {
        float q = exp2f(rintf(4.f*m));
        #pragma unroll
        for (int k = 0; k < 4; k++) o[k] = floorf(iv[k]/q)*q;
        break; }
    case 11: {
        #pragma unroll
        for (int k = 0; k < 4; k++){
            int ivi = min(max((int)rintf(iv[k]), 0), 255);
            o[k] = lut[ivi];
        }
        break; }
    case 12: {
        float sc = 255.f / fmaxf(hi - lo, 1e-6f);
        #pragma unroll
        for (int k = 0; k < 4; k++)
            o[k] = (hi > lo) ? clip255((iv[k] - lo) * sc) : iv[k];
        break; }
    default:
        #pragma unroll
        for (int k = 0; k < 4; k++) o[k] = iv[k];
        break;
    }
}

// ---------------- K1: slice partials over x (2048 blocks) ----------------
__global__ void k1_stats(const float* __restrict__ x, const int* __restrict__ op,
                         const int* __restrict__ mask, float* __restrict__ wsf)
{
    __shared__ float red[4];
    __shared__ int sh[1536];
    int* ints = (int*)wsf;
    float* psum0 = wsf + OFF_PSUM0;
    float* pmin0 = wsf + OFF_PMIN0;
    float* pmax0 = wsf + OFF_PMAX0;
    int* phist0 = (int*)wsf + OFF_PHIST0;
    int* hist1  = (int*)wsf + OFF_HIST1;

    int blk = blockIdx.x, tid = threadIdx.x;
    if (tid < 24) hist1[blk*24 + tid] = 0;      // zero 64*768 ints across 2048 blocks

    int b = blk >> 5, s = blk & 31;
    int j = op[b], ap = mask[b];
    bool needSum  = ap && (j == 8);
    bool needMM   = ap && (j == 12);
    bool needHist = ap && (j == 11);
    const float* img = x + (size_t)b * CHW;
    int p0 = s * SCH;
    const float GW[3] = {0.299f, 0.587f, 0.114f};

    float mx = 0.f, gs = 0.f;
    for (int c = 0; c < 3; c++){
        const float* pl = img + c*HWp + p0;
        float lo = 3.4e38f, hi = 0.f, cs = 0.f;
        for (int p = tid*4; p < SCH; p += 1024){
            float4 v = *(const float4*)(pl + p);
            float m4 = fmaxf(fmaxf(v.x, v.y), fmaxf(v.z, v.w));
            mx = fmaxf(mx, m4);
            if (needMM){ hi = fmaxf(hi, m4); lo = fminf(lo, fminf(fminf(v.x,v.y), fminf(v.z,v.w))); }
            if (needSum) cs += (v.x + v.y) + (v.z + v.w);
        }
        if (needSum) gs += GW[c] * cs;
        if (needMM){
            float l = blk_reduce(lo, red, tid, 1);
            if (!tid) pmin0[blk*3 + c] = l;
            float h = blk_reduce(hi, red, tid, 2);
            if (!tid) pmax0[blk*3 + c] = h;
        }
    }
    float bm = blk_reduce(mx, red, tid, 2);
    if (!tid) atomicMax(&ints[OFF_MAXB], __float_as_int(bm));   // bm>=0 -> int order == float order
    if (needSum){
        float t = blk_reduce(gs, red, tid, 0);
        if (!tid) psum0[blk] = t;
    }
    if (needHist){
        for (int i = tid; i < 1536; i += 256) sh[i] = 0;
        __syncthreads();
        for (int c = 0; c < 3; c++){
            const float* pl = img + c*HWp + p0;
            for (int p = tid; p < SCH; p += 256){
                float v = pl[p];
                atomicAdd(&sh[c*256 + min(max((int)rintf(v), 0), 255)], 1);
                atomicAdd(&sh[768 + c*256 + min(max((int)rintf(v*255.f), 0), 255)], 1);
            }
        }
        __syncthreads();
        for (int i = tid; i < 1536; i += 256) phist0[blk*1536 + i] = sh[i];
    }
}

// ---------------- K2: per-block finalize0 + apply depth0 + per-wave stats1 partials ----------------
__global__ void k2_apply0(const float* __restrict__ x, const float* __restrict__ ra,
                          const int* __restrict__ op, const int* __restrict__ mask,
                          float* __restrict__ wsf)
{
    __shared__ float red[4];
    __shared__ int   shh[256];
    __shared__ float slut[256];
    __shared__ int   h255;
    const int* ints = (const int*)wsf;
    const float* psum0 = wsf + OFF_PSUM0;
    const float* pmin0 = wsf + OFF_PMIN0;
    const float* pmax0 = wsf + OFF_PMAX0;
    const int* phist0 = (const int*)wsf + OFF_PHIST0;
    int* hist1 = (int*)wsf + OFF_HIST1;
    float* psum1 = wsf + OFF_PSUM1;
    float* pmin1 = wsf + OFF_PMIN1;
    float* pmax1 = wsf + OFF_PMAX1;
    float* inter = wsf + OFF_INTER;

    int t = blockIdx.x, tid = threadIdx.x;
    int b = t / TPI;
    int r = t - b*TPI;
    int c = r / TPC;
    int p = (r - c*TPC)*1024 + tid*4;

    const float* img = x + (size_t)b*CHW;
    float4 v4 = *(const float4*)(img + c*HWp + p);   // prefetch before stats work

    float scl = (__int_as_float(ints[OFF_MAXB]) <= 1.0f) ? 255.f : 1.f;
    int j = op[b], ap = mask[b];
    float m = ra[b];

    float mu = 0.f, lo = 0.f, hi = 0.f;
    const float* lut = nullptr;
    if (ap){
        if (j == 8){
            float v = (tid < 32) ? psum0[b*32 + tid] : 0.f;
            mu = blk_reduce(v, red, tid, 0) * scl * (1.f/(float)HWp);
        } else if (j == 12){
            float v  = (tid < 32) ? pmin0[(b*32 + tid)*3 + c] : 3.4e38f;
            lo = blk_reduce(v, red, tid, 1) * scl;
            float v2 = (tid < 32) ? pmax0[(b*32 + tid)*3 + c] : 0.f;
            hi = blk_reduce(v2, red, tid, 2) * scl;
        } else if (j == 11){
            int d = (scl == 255.f) ? 1 : 0;
            const int* ph = phist0 + d*768 + c*256 + tid;
            int sum = 0;
            #pragma unroll 8
            for (int s = 0; s < 32; s++) sum += ph[(b*32 + s)*1536];
            lut = lut_scan(sum, shh, slut, tid, &h255);
        }
    }

    float o[4];
    apply_body(img, c, p, v4, j, ap, m, scl, mu, lo, hi, lut, o);
    float4 w = {o[0], o[1], o[2], o[3]};
    *(float4*)(inter + (size_t)b*CHW + c*HWp + p) = w;

    // fused stats1 partials on outputs: per-wave slots
    int j1 = op[NB + b], ap1 = mask[NB + b];
    if (ap1 && (j1 == 8 || j1 == 11 || j1 == 12)){
        const float GW[3] = {0.299f, 0.587f, 0.114f};
        int wv = tid >> 6;
        if (j1 == 8){
            float s4 = (o[0] + o[1]) + (o[2] + o[3]);
            float ws = wred(s4, 0);
            if ((tid & 63) == 0) psum1[t*4 + wv] = ws * GW[c];
        } else if (j1 == 12){
            float l4 = fminf(fminf(o[0],o[1]), fminf(o[2],o[3]));
            float h4 = fmaxf(fmaxf(o[0],o[1]), fmaxf(o[2],o[3]));
            float wl = wred(l4, 1);
            float wh = wred(h4, 2);
            if ((tid & 63) == 0){ pmin1[t*4 + wv] = wl; pmax1[t*4 + wv] = wh; }
        } else {
            __syncthreads();
            shh[tid] = 0;
            __syncthreads();
            #pragma unroll
            for (int k = 0; k < 4; k++)
                atomicAdd(&shh[min(max((int)rintf(o[k]), 0), 255)], 1);
            __syncthreads();
            int v = shh[tid];
            if (v) atomicAdd(&hist1[b*768 + c*256 + tid], v);
        }
    }
}

// ---------------- K3: per-block finalize1 + apply depth1 -> out ----------------
__global__ void k3_apply1(const float* __restrict__ ra, const int* __restrict__ op,
                          const int* __restrict__ mask, float* __restrict__ out,
                          float* __restrict__ wsf)
{
    __shared__ float red[4];
    __shared__ int   shh[256];
    __shared__ float slut[256];
    __shared__ int   h255;
    const int* hist1 = (const int*)wsf + OFF_HIST1;
    const float* psum1 = wsf + OFF_PSUM1;
    const float* pmin1 = wsf + OFF_PMIN1;
    const float* pmax1 = wsf + OFF_PMAX1;
    const float* inter = wsf + OFF_INTER;

    int t = blockIdx.x, tid = threadIdx.x;
    int b = t / TPI;
    int r = t - b*TPI;
    int c = r / TPC;
    int p = (r - c*TPC)*1024 + tid*4;

    const float* img = inter + (size_t)b*CHW;
    float4 v4 = *(const float4*)(img + c*HWp + p);   // prefetch before stats work

    int j = op[NB + b], ap = mask[NB + b];
    float m = ra[NB + b];

    float mu = 0.f, lo = 0.f, hi = 0.f;
    const float* lut = nullptr;
    if (ap){
        if (j == 8){
            float v = 0.f;
            for (int i = tid; i < TPI*4; i += 256) v += psum1[b*TPI*4 + i];
            mu = blk_reduce(v, red, tid, 0) * (1.f/(float)HWp);
        } else if (j == 12){
            float v  = (tid < TPC*4) ? pmin1[(b*TPI + c*TPC)*4 + tid] : 3.4e38f;
            lo = blk_reduce(v, red, tid, 1);
            float v2 = (tid < TPC*4) ? pmax1[(b*TPI + c*TPC)*4 + tid] : 0.f;
            hi = blk_reduce(v2, red, tid, 2);
        } else if (j == 11){
            lut = lut_scan(hist1[b*768 + c*256 + tid], shh, slut, tid, &h255);
        }
    }

    float o[4];
    apply_body(img, c, p, v4, j, ap, m, 1.f, mu, lo, hi, lut, o);
    float4 w;
    w.x = fminf(fmaxf(o[0]*(1.f/255.f), 0.f), 1.f);
    w.y = fminf(fmaxf(o[1]*(1.f/255.f), 0.f), 1.f);
    w.z = fminf(fmaxf(o[2]*(1.f/255.f), 0.f), 1.f);
    w.w = fminf(fmaxf(o[3]*(1.f/255.f), 0.f), 1.f);
    *(float4*)(out + (size_t)b*CHW + c*HWp + p) = w;
}

extern "C" void kernel_launch(void* const* d_in, const int* in_sizes, int n_in,
                              void* d_out, int out_size, void* d_ws, size_t ws_size,
                              hipStream_t stream) {
    const float* x    = (const float*)d_in[0];
    const float* ra   = (const float*)d_in[1];
    const int*   op   = (const int*)d_in[2];
    const int*   mask = (const int*)d_in[3];
    float* out = (float*)d_out;
    float* wsf = (float*)d_ws;

    k1_stats <<<NSL, 256, 0, stream>>>(x, op, mask, wsf);
    k2_apply0<<<NT,  256, 0, stream>>>(x, ra, op, mask, wsf);
    k3_apply1<<<NT,  256, 0, stream>>>(ra, op, mask, out, wsf);
}

// Round 12
// 143.613 us; speedup vs baseline: 1.0780x; 1.0105x over previous
//
#include <hip/hip_runtime.h>

#define WID 224
#define HGT 224
#define HWp 50176          // 224*224
#define CHW 150528         // 3*HWp
#define NB  64
#define NSL 2048           // 64 images x 32 slices (K1)
#define SCH 1568           // HWp/32
#define TPI2 75            // tiles per image (K2/K3): 25 per channel (24 full 2048px + 1 half)
#define TPC2 25
#define NT2 4800           // NB*TPI2

// workspace offsets (4B units)
#define OFF_MAXB   0       // ints[0]: global max (float bits, atomicMax; poison is negative -> no init)
#define OFF_HIST1  256     // ints: 64*768 -> ends 49408
#define OFF_PSUM0  49408   // floats: 2048
#define OFF_PMIN0  51456   // floats: 2048*3
#define OFF_PMAX0  57600   // floats: 2048*3
#define OFF_PHIST0 63744   // ints: 2048*1536 (dual hist per slice: [0..768)=x1, [768..1536)=x255)
#define OFF_PSUM1  3209472 // floats: 4800*4 per-wave partials (region oversized, layout unchanged)
#define OFF_PMIN1  3247104 // floats: 4800*4
#define OFF_PMAX1  3284736 // floats: 4800*4
#define OFF_INTER  3322368 // floats: 9,633,792

__device__ __forceinline__ float clip255(float v){ return fminf(fmaxf(v, 0.f), 255.f); }

// wave-level reduce (64 lanes); lane 0 holds result
__device__ __forceinline__ float wred(float v, int op){
    #pragma unroll
    for (int o = 32; o > 0; o >>= 1){
        float u = __shfl_down(v, o);
        v = (op==0) ? v+u : (op==1 ? fminf(v,u) : fmaxf(v,u));
    }
    return v;
}

// block reduce for 256 threads: shuffle + 4-slot LDS combine (2 barriers)
__device__ __forceinline__ float blk_reduce(float v, float* red, int tid, int op){
    float w = wred(v, op);
    if ((tid & 63) == 0) red[tid >> 6] = w;
    __syncthreads();
    float a = red[0], b = red[1], c = red[2], d = red[3];
    float r = (op==0) ? (a+b)+(c+d) : (op==1 ? fminf(fminf(a,b),fminf(c,d)) : fmaxf(fmaxf(a,b),fmaxf(c,d)));
    __syncthreads();
    return r;
}

// Parallel LUT build from per-thread bin count hv (thread tid owns bin tid).
__device__ __forceinline__ const float* lut_scan(int hv, int* shh, float* slut, int tid, int* h255){
    if (tid == 255) *h255 = hv;
    shh[tid] = hv;
    __syncthreads();
    #pragma unroll
    for (int off = 1; off < 256; off <<= 1){
        int v = (tid >= off) ? shh[tid-off] : 0;
        __syncthreads();
        shh[tid] += v;
        __syncthreads();
    }
    int cum = shh[tid] - hv;                 // exclusive prefix
    int step = (HWp - *h255) / 255;
    int l = (step > 0) ? min(max((cum + (step >> 1)) / step, 0), 255) : tid;
    slut[tid] = (float)l;
    __syncthreads();
    return slut;
}

__device__ __forceinline__ float samp(const float* __restrict__ pl, float yi, float xi, float scl){
    if (xi < 0.f || xi > (float)(WID-1) || yi < 0.f || yi > (float)(HGT-1)) return 0.f;
    return pl[(int)yi * WID + (int)xi] * scl;
}

// Compute 4 output px for plane-offset p of channel c; v4 = raw (unscaled) input float4.
__device__ __forceinline__ void apply_body(const float* __restrict__ img,
                                           int c, int p, float4 v4,
                                           int j, int ap, float m, float scl,
                                           float mu, float lo, float hi,
                                           const float* lut,
                                           float o[4])
{
    int y = p / WID;
    int x = p - y*WID;
    const float* pl = img + c*HWp;
    float vr[4] = {v4.x, v4.y, v4.z, v4.w};
    float iv[4] = {v4.x*scl, v4.y*scl, v4.z*scl, v4.w*scl};

    if (!ap) {
        #pragma unroll
        for (int k = 0; k < 4; k++) o[k] = iv[k];
        return;
    }
    switch (j){
    case 0: case 2: {   // shear_x / translate_x: sy=y exactly (wy=0); sx steps by exactly 1
        float off = (j==0) ? (-0.3f + 0.6f*m)*(float)y
                           : (-0.45f + 0.9f*m)*(float)WID;
        float sx0 = (float)x + off;
        float x0f = floorf(sx0);
        float wx  = sx0 - x0f;
        int   x0  = (int)x0f;
        const float* row = pl + y*WID;
        float v[5];
        if (x0 >= 0 && x0 <= WID-5){            // interior: unconditional loads
            #pragma unroll
            for (int k = 0; k < 5; k++) v[k] = row[x0+k]*scl;
        } else {
            #pragma unroll
            for (int k = 0; k < 5; k++){
                int col = x0 + k;
                v[k] = (col >= 0 && col < WID) ? row[col]*scl : 0.f;
            }
        }
        #pragma unroll
        for (int k = 0; k < 4; k++) o[k] = v[k]*(1.f-wx) + v[k+1]*wx;
        break; }
    case 3: {           // translate_y: sx=x exactly (wx=0); wy constant per row
        float ff  = (-0.45f + 0.9f*m)*(float)HGT;
        float sy0 = (float)y + ff;
        float y0f = floorf(sy0);
        float wy  = sy0 - y0f;
        int   y0  = (int)y0f;
        float4 t4 = {0.f,0.f,0.f,0.f}, b4 = {0.f,0.f,0.f,0.f};
        if (y0   >= 0 && y0   < HGT) t4 = *(const float4*)(pl + y0*WID + x);
        if (y0+1 >= 0 && y0+1 < HGT) b4 = *(const float4*)(pl + (y0+1)*WID + x);
        float tt[4] = {t4.x,t4.y,t4.z,t4.w}, bb[4] = {b4.x,b4.y,b4.z,b4.w};
        #pragma unroll
        for (int k = 0; k < 4; k++) o[k] = (tt[k]*scl)*(1.f-wy) + (bb[k]*scl)*wy;
        break; }
    case 1: {           // shear_y: sx=x exactly (wx=0); 2 loads per px
        float dd = -0.3f + 0.6f*m;
        #pragma unroll
        for (int k = 0; k < 4; k++){
            float sy = dd*(float)(x+k) + (float)y;
            float y0f = floorf(sy);
            float wy  = sy - y0f;
            int   y0  = (int)y0f;
            int col = x + k;
            float tv = (y0   >= 0 && y0   < HGT) ? pl[y0*WID + col]*scl : 0.f;
            float bv = (y0+1 >= 0 && y0+1 < HGT) ? pl[(y0+1)*WID + col]*scl : 0.f;
            o[k] = tv*(1.f-wy) + bv*wy;
        }
        break; }
    case 4: {           // rotate: general bilinear
        float deg = -30.f + 60.f*m;
        float rad = deg * (float)(3.14159265358979323846/180.0);
        float cs = cosf(rad), sn = sinf(rad);
        float cx = (WID-1)*0.5f, cy = (HGT-1)*0.5f;
        float a = cs, bb = sn, dd = -sn, ee = cs;
        float cc = cx - cs*cx - sn*cy;
        float ff = cy + sn*cx - cs*cy;
        float yf = (float)y;
        #pragma unroll
        for (int k = 0; k < 4; k++){
            float xf = (float)(x + k);
            float sx = a*xf + bb*yf + cc;
            float sy = dd*xf + ee*yf + ff;
            float x0f = floorf(sx), y0f = floorf(sy);
            float wx = sx - x0f, wy = sy - y0f;
            float v00 = samp(pl, y0f,     x0f,     scl);
            float v01 = samp(pl, y0f,     x0f+1.f, scl);
            float v10 = samp(pl, y0f+1.f, x0f,     scl);
            float v11 = samp(pl, y0f+1.f, x0f+1.f, scl);
            float top = v00*(1.f-wx) + v01*wx;
            float bot = v10*(1.f-wx) + v11*wx;
            o[k] = top*(1.f-wy) + bot*wy;
        }
        break; }
    case 5: {
        float f = 0.1f + 1.8f*m;
        #pragma unroll
        for (int k = 0; k < 4; k++) o[k] = clip255(iv[k]*f);
        break; }
    case 6: {
        float4 r4 = *(const float4*)(img + p);
        float4 g4 = *(const float4*)(img + HWp + p);
        float4 b4 = *(const float4*)(img + 2*HWp + p);
        float rr[4] = {r4.x*scl, r4.y*scl, r4.z*scl, r4.w*scl};
        float gg[4] = {g4.x*scl, g4.y*scl, g4.z*scl, g4.w*scl};
        float bl[4] = {b4.x*scl, b4.y*scl, b4.z*scl, b4.w*scl};
        float f = 0.1f + 1.8f*m;
        #pragma unroll
        for (int k = 0; k < 4; k++){
            float g = 0.299f*rr[k] + 0.587f*gg[k] + 0.114f*bl[k];
            o[k] = clip255(g + f*(iv[k] - g));
        }
        break; }
    case 7: {           // sharpness: 2 float4 + 6 scalar edge loads
        float f = 0.1f + 1.8f*m;
        if (y == 0 || y == HGT-1){
            #pragma unroll
            for (int k = 0; k < 4; k++) o[k] = iv[k];
        } else {
            float4 up4 = *(const float4*)(pl + p - WID);
            float4 dn4 = *(const float4*)(pl + p + WID);
            bool hasL = (x > 0), hasR = (x < WID-4);
            float u0 = hasL ? pl[p-WID-1] : 0.f, u5 = hasR ? pl[p-WID+4] : 0.f;
            float c0 = hasL ? pl[p-1]     : 0.f, c5 = hasR ? pl[p+4]     : 0.f;
            float d0 = hasL ? pl[p+WID-1] : 0.f, d5 = hasR ? pl[p+WID+4] : 0.f;
            float uu[6] = {u0, up4.x, up4.y, up4.z, up4.w, u5};
            float cc[6] = {c0, vr[0], vr[1], vr[2], vr[3], c5};
            float dd[6] = {d0, dn4.x, dn4.y, dn4.z, dn4.w, d5};
            #pragma unroll
            for (int k = 0; k < 4; k++){
                int xx = x + k;
                if (xx == 0 || xx == WID-1) o[k] = iv[k];
                else {
                    float s8 = uu[k]+uu[k+1]+uu[k+2] + cc[k]+cc[k+2] + dd[k]+dd[k+1]+dd[k+2];
                    float blur = (s8*scl + 5.f*iv[k]) * (1.f/13.f);
                    o[k] = clip255(blur + f*(iv[k] - blur));
                }
            }
        }
        break; }
    case 8: {
        float f = 0.1f + 1.8f*m;
        #pragma unroll
        for (int k = 0; k < 4; k++) o[k] = clip255(mu + f*(iv[k] - mu));
        break; }
    case 9: {
        float thr = 256.f*m;
        #pragma unroll
        for (int k = 0; k < 4; k++) o[k] = (iv[k] < thr) ? iv[k] : 255.f - iv[k];
        break; }
    case 10: {
        float q = exp2f(rintf(4.f*m));
        #pragma unroll
        for (int k = 0; k < 4; k++) o[k] = floorf(iv[k]/q)*q;
        break; }
    case 11: {
        #pragma unroll
        for (int k = 0; k < 4; k++){
            int ivi = min(max((int)rintf(iv[k]), 0), 255);
            o[k] = lut[ivi];
        }
        break; }
    case 12: {
        float sc = 255.f / fmaxf(hi - lo, 1e-6f);
        #pragma unroll
        for (int k = 0; k < 4; k++)
            o[k] = (hi > lo) ? clip255((iv[k] - lo) * sc) : iv[k];
        break; }
    default:
        #pragma unroll
        for (int k = 0; k < 4; k++) o[k] = iv[k];
        break;
    }
}

// ---------------- K1: slice partials over x (2048 blocks); single pass ----------------
__global__ void k1_stats(const float* __restrict__ x, const int* __restrict__ op,
                         const int* __restrict__ mask, float* __restrict__ wsf)
{
    __shared__ float red[4];
    __shared__ int sh[1536];
    int* ints = (int*)wsf;
    float* psum0 = wsf + OFF_PSUM0;
    float* pmin0 = wsf + OFF_PMIN0;
    float* pmax0 = wsf + OFF_PMAX0;
    int* phist0 = (int*)wsf + OFF_PHIST0;
    int* hist1  = (int*)wsf + OFF_HIST1;

    int blk = blockIdx.x, tid = threadIdx.x;
    if (tid < 24) hist1[blk*24 + tid] = 0;      // zero 64*768 ints across 2048 blocks

    int b = blk >> 5, s = blk & 31;
    int j = op[b], ap = mask[b];
    bool needSum  = ap && (j == 8);
    bool needMM   = ap && (j == 12);
    bool needHist = ap && (j == 11);
    const float* img = x + (size_t)b * CHW;
    int p0 = s * SCH;
    const float GW[3] = {0.299f, 0.587f, 0.114f};

    if (needHist){
        for (int i = tid; i < 1536; i += 256) sh[i] = 0;
        __syncthreads();
    }

    float mx = 0.f, gs = 0.f;
    for (int c = 0; c < 3; c++){
        const float* pl = img + c*HWp + p0;
        float lo = 3.4e38f, hi = 0.f, cs = 0.f;
        for (int p = tid*4; p < SCH; p += 1024){
            float4 v = *(const float4*)(pl + p);
            float m4 = fmaxf(fmaxf(v.x, v.y), fmaxf(v.z, v.w));
            mx = fmaxf(mx, m4);
            if (needMM){ hi = fmaxf(hi, m4); lo = fminf(lo, fminf(fminf(v.x,v.y), fminf(v.z,v.w))); }
            if (needSum) cs += (v.x + v.y) + (v.z + v.w);
            if (needHist){
                float vv[4] = {v.x, v.y, v.z, v.w};
                #pragma unroll
                for (int k = 0; k < 4; k++){
                    atomicAdd(&sh[c*256 + min(max((int)rintf(vv[k]), 0), 255)], 1);
                    atomicAdd(&sh[768 + c*256 + min(max((int)rintf(vv[k]*255.f), 0), 255)], 1);
                }
            }
        }
        if (needSum) gs += GW[c] * cs;
        if (needMM){
            float l = blk_reduce(lo, red, tid, 1);
            if (!tid) pmin0[blk*3 + c] = l;
            float h = blk_reduce(hi, red, tid, 2);
            if (!tid) pmax0[blk*3 + c] = h;
        }
    }
    float bm = blk_reduce(mx, red, tid, 2);
    if (!tid) atomicMax(&ints[OFF_MAXB], __float_as_int(bm));   // bm>=0 -> int order == float order
    if (needSum){
        float t = blk_reduce(gs, red, tid, 0);
        if (!tid) psum0[blk] = t;
    }
    if (needHist){
        __syncthreads();
        for (int i = tid; i < 1536; i += 256) phist0[blk*1536 + i] = sh[i];
    }
}

// ---------------- K2: finalize0 + apply depth0 (8 px/thread) + per-wave stats1 partials ----------------
__global__ void k2_apply0(const float* __restrict__ x, const float* __restrict__ ra,
                          const int* __restrict__ op, const int* __restrict__ mask,
                          float* __restrict__ wsf)
{
    __shared__ float red[4];
    __shared__ int   shh[256];
    __shared__ float slut[256];
    __shared__ int   h255;
    const int* ints = (const int*)wsf;
    const float* psum0 = wsf + OFF_PSUM0;
    const float* pmin0 = wsf + OFF_PMIN0;
    const float* pmax0 = wsf + OFF_PMAX0;
    const int* phist0 = (const int*)wsf + OFF_PHIST0;
    int* hist1 = (int*)wsf + OFF_HIST1;
    float* psum1 = wsf + OFF_PSUM1;
    float* pmin1 = wsf + OFF_PMIN1;
    float* pmax1 = wsf + OFF_PMAX1;
    float* inter = wsf + OFF_INTER;

    int t = blockIdx.x, tid = threadIdx.x;
    int b = t / TPI2;
    int r = t - b*TPI2;
    int c = r / TPC2;
    int q = r - c*TPC2;
    int p  = q*2048 + tid*4;
    int p2 = p + 1024;
    bool full = (q < TPC2-1);                   // q==24: half tile (chunk0 only)

    const float* img = x + (size_t)b*CHW;
    const float* pl  = img + c*HWp;
    float4 va = *(const float4*)(pl + p);       // prefetch both chunks
    float4 vb = full ? *(const float4*)(pl + p2) : make_float4(0.f,0.f,0.f,0.f);

    float scl = (__int_as_float(ints[OFF_MAXB]) <= 1.0f) ? 255.f : 1.f;
    int j = op[b], ap = mask[b];
    float m = ra[b];

    float mu = 0.f, lo = 0.f, hi = 0.f;
    const float* lut = nullptr;
    if (ap){
        if (j == 8){
            float v = (tid < 32) ? psum0[b*32 + tid] : 0.f;
            mu = blk_reduce(v, red, tid, 0) * scl * (1.f/(float)HWp);
        } else if (j == 12){
            float v  = (tid < 32) ? pmin0[(b*32 + tid)*3 + c] : 3.4e38f;
            lo = blk_reduce(v, red, tid, 1) * scl;
            float v2 = (tid < 32) ? pmax0[(b*32 + tid)*3 + c] : 0.f;
            hi = blk_reduce(v2, red, tid, 2) * scl;
        } else if (j == 11){
            int d = (scl == 255.f) ? 1 : 0;
            const int* ph = phist0 + d*768 + c*256 + tid;
            int sum = 0;
            #pragma unroll 8
            for (int s = 0; s < 32; s++) sum += ph[(b*32 + s)*1536];
            lut = lut_scan(sum, shh, slut, tid, &h255);
        }
    }

    float oa[4], ob[4] = {0.f,0.f,0.f,0.f};
    apply_body(img, c, p, va, j, ap, m, scl, mu, lo, hi, lut, oa);
    if (full) apply_body(img, c, p2, vb, j, ap, m, scl, mu, lo, hi, lut, ob);
    float* dst = inter + (size_t)b*CHW + c*HWp;
    *(float4*)(dst + p) = make_float4(oa[0], oa[1], oa[2], oa[3]);
    if (full) *(float4*)(dst + p2) = make_float4(ob[0], ob[1], ob[2], ob[3]);

    // fused stats1 partials on outputs (both chunks combined in-thread)
    int j1 = op[NB + b], ap1 = mask[NB + b];
    if (ap1 && (j1 == 8 || j1 == 11 || j1 == 12)){
        const float GW[3] = {0.299f, 0.587f, 0.114f};
        int wv = tid >> 6;
        if (j1 == 8){
            float s8 = (oa[0]+oa[1])+(oa[2]+oa[3]);
            if (full) s8 += (ob[0]+ob[1])+(ob[2]+ob[3]);
            float ws = wred(s8, 0);
            if ((tid & 63) == 0) psum1[t*4 + wv] = ws * GW[c];
        } else if (j1 == 12){
            float l8 = fminf(fminf(oa[0],oa[1]), fminf(oa[2],oa[3]));
            float h8 = fmaxf(fmaxf(oa[0],oa[1]), fmaxf(oa[2],oa[3]));
            if (full){
                l8 = fminf(l8, fminf(fminf(ob[0],ob[1]), fminf(ob[2],ob[3])));
                h8 = fmaxf(h8, fmaxf(fmaxf(ob[0],ob[1]), fmaxf(ob[2],ob[3])));
            }
            float wl = wred(l8, 1);
            float wh = wred(h8, 2);
            if ((tid & 63) == 0){ pmin1[t*4 + wv] = wl; pmax1[t*4 + wv] = wh; }
        } else {
            __syncthreads();
            shh[tid] = 0;
            __syncthreads();
            #pragma unroll
            for (int k = 0; k < 4; k++)
                atomicAdd(&shh[min(max((int)rintf(oa[k]), 0), 255)], 1);
            if (full){
                #pragma unroll
                for (int k = 0; k < 4; k++)
                    atomicAdd(&shh[min(max((int)rintf(ob[k]), 0), 255)], 1);
            }
            __syncthreads();
            int v = shh[tid];
            if (v) atomicAdd(&hist1[b*768 + c*256 + tid], v);
        }
    }
}

// ---------------- K3: finalize1 + apply depth1 (8 px/thread) -> out ----------------
__global__ void k3_apply1(const float* __restrict__ ra, const int* __restrict__ op,
                          const int* __restrict__ mask, float* __restrict__ out,
                          float* __restrict__ wsf)
{
    __shared__ float red[4];
    __shared__ int   shh[256];
    __shared__ float slut[256];
    __shared__ int   h255;
    const int* hist1 = (const int*)wsf + OFF_HIST1;
    const float* psum1 = wsf + OFF_PSUM1;
    const float* pmin1 = wsf + OFF_PMIN1;
    const float* pmax1 = wsf + OFF_PMAX1;
    const float* inter = wsf + OFF_INTER;

    int t = blockIdx.x, tid = threadIdx.x;
    int b = t / TPI2;
    int r = t - b*TPI2;
    int c = r / TPC2;
    int q = r - c*TPC2;
    int p  = q*2048 + tid*4;
    int p2 = p + 1024;
    bool full = (q < TPC2-1);

    const float* img = inter + (size_t)b*CHW;
    const float* pl  = img + c*HWp;
    float4 va = *(const float4*)(pl + p);
    float4 vb = full ? *(const float4*)(pl + p2) : make_float4(0.f,0.f,0.f,0.f);

    int j = op[NB + b], ap = mask[NB + b];
    float m = ra[NB + b];

    float mu = 0.f, lo = 0.f, hi = 0.f;
    const float* lut = nullptr;
    if (ap){
        if (j == 8){
            float v = 0.f;
            for (int i = tid; i < TPI2*4; i += 256) v += psum1[b*TPI2*4 + i];
            mu = blk_reduce(v, red, tid, 0) * (1.f/(float)HWp);
        } else if (j == 12){
            float v  = (tid < TPC2*4) ? pmin1[(b*TPI2 + c*TPC2)*4 + tid] : 3.4e38f;
            lo = blk_reduce(v, red, tid, 1);
            float v2 = (tid < TPC2*4) ? pmax1[(b*TPI2 + c*TPC2)*4 + tid] : 0.f;
            hi = blk_reduce(v2, red, tid, 2);
        } else if (j == 11){
            lut = lut_scan(hist1[b*768 + c*256 + tid], shh, slut, tid, &h255);
        }
    }

    float oa[4], ob[4];
    apply_body(img, c, p, va, j, ap, m, 1.f, mu, lo, hi, lut, oa);
    if (full) apply_body(img, c, p2, vb, j, ap, m, 1.f, mu, lo, hi, lut, ob);

    float* dst = out + (size_t)b*CHW + c*HWp;
    float4 w;
    w.x = fminf(fmaxf(oa[0]*(1.f/255.f), 0.f), 1.f);
    w.y = fminf(fmaxf(oa[1]*(1.f/255.f), 0.f), 1.f);
    w.z = fminf(fmaxf(oa[2]*(1.f/255.f), 0.f), 1.f);
    w.w = fminf(fmaxf(oa[3]*(1.f/255.f), 0.f), 1.f);
    *(float4*)(dst + p) = w;
    if (full){
        float4 w2;
        w2.x = fminf(fmaxf(ob[0]*(1.f/255.f), 0.f), 1.f);
        w2.y = fminf(fmaxf(ob[1]*(1.f/255.f), 0.f), 1.f);
        w2.z = fminf(fmaxf(ob[2]*(1.f/255.f), 0.f), 1.f);
        w2.w = fminf(fmaxf(ob[3]*(1.f/255.f), 0.f), 1.f);
        *(float4*)(dst + p2) = w2;
    }
}

extern "C" void kernel_launch(void* const* d_in, const int* in_sizes, int n_in,
                              void* d_out, int out_size, void* d_ws, size_t ws_size,
                              hipStream_t stream) {
    const float* x    = (const float*)d_in[0];
    const float* ra   = (const float*)d_in[1];
    const int*   op   = (const int*)d_in[2];
    const int*   mask = (const int*)d_in[3];
    float* out = (float*)d_out;
    float* wsf = (float*)d_ws;

    k1_stats <<<NSL, 256, 0, stream>>>(x, op, mask, wsf);
    k2_apply0<<<NT2, 256, 0, stream>>>(x, ra, op, mask, wsf);
    k3_apply1<<<NT2, 256, 0, stream>>>(ra, op, mask, out, wsf);
}